// Round 2
// baseline (38.901 us; speedup 1.0000x reference)
//
#include <hip/hip_runtime.h>

#define NBLOCKS 2048

__global__ __launch_bounds__(256) void focal_partial_kernel(
    const float* __restrict__ x,
    const int*   __restrict__ tgt,     // harness pushes integer inputs as int32
    const float* __restrict__ alpha,
    float* __restrict__ ws,
    int N)
{
    const int tid     = blockIdx.x * blockDim.x + threadIdx.x;
    const int lo      = threadIdx.x & 7;        // lane within 8-lane row-group
    const int group   = tid >> 3;               // one group per row
    const int ngroups = (gridDim.x * blockDim.x) >> 3;

    float acc = 0.0f;

    for (int row = group; row < N; row += ngroups) {
        // 64 lanes of a wave read 1024 contiguous bytes (8 rows x 128B)
        const float4 v = *reinterpret_cast<const float4*>(
            x + (size_t)row * 32 + (size_t)lo * 4);

        // row max via 8-lane butterfly
        float m = fmaxf(fmaxf(v.x, v.y), fmaxf(v.z, v.w));
        m = fmaxf(m, __shfl_xor(m, 1));
        m = fmaxf(m, __shfl_xor(m, 2));
        m = fmaxf(m, __shfl_xor(m, 4));

        // sum of exp
        float s = expf(v.x - m) + expf(v.y - m) + expf(v.z - m) + expf(v.w - m);
        s += __shfl_xor(s, 1);
        s += __shfl_xor(s, 2);
        s += __shfl_xor(s, 4);

        const int t  = tgt[row] & 31;  // class index (mask is a no-op for valid data)
        const int tl = t >> 2;         // which lane of the group owns column t
        const int te = t & 3;          // which element of its float4

        float xt = (te == 0) ? v.x : (te == 1) ? v.y : (te == 2) ? v.z : v.w;
        xt = __shfl(xt, tl, 8);        // broadcast from owner lane within group

        if (lo == 0) {
            const float d    = xt - m;          // logit minus max
            const float logs = logf(s);
            const float ce   = logs - d;        // -log_softmax[t]
            const float pt   = expf(d) / s;     // softmax prob of true class
            const float om   = 1.0f - pt;
            acc += alpha[t] * om * om * ce;     // GAMMA = 2
        }
    }

    // deterministic block tree-reduction
    __shared__ float red[256];
    red[threadIdx.x] = acc;
    __syncthreads();
    for (int stride = 128; stride > 0; stride >>= 1) {
        if (threadIdx.x < stride)
            red[threadIdx.x] += red[threadIdx.x + stride];
        __syncthreads();
    }
    if (threadIdx.x == 0) ws[blockIdx.x] = red[0];
}

__global__ __launch_bounds__(256) void focal_final_kernel(
    const float* __restrict__ ws, int nparts, float* __restrict__ out, float invN)
{
    __shared__ float red[256];
    float acc = 0.0f;
    for (int i = threadIdx.x; i < nparts; i += 256) acc += ws[i];
    red[threadIdx.x] = acc;
    __syncthreads();
    for (int stride = 128; stride > 0; stride >>= 1) {
        if (threadIdx.x < stride)
            red[threadIdx.x] += red[threadIdx.x + stride];
        __syncthreads();
    }
    if (threadIdx.x == 0) out[0] = red[0] * invN;
}

extern "C" void kernel_launch(void* const* d_in, const int* in_sizes, int n_in,
                              void* d_out, int out_size, void* d_ws, size_t ws_size,
                              hipStream_t stream)
{
    const float* x     = (const float*)d_in[0];   // [N,32] fp32
    const int*   tgt   = (const int*)d_in[1];     // [N] int32 (harness converts int64)
    const float* alpha = (const float*)d_in[2];   // [32] fp32
    const int    N     = in_sizes[1];             // 1048576
    float*       ws    = (float*)d_ws;
    float*       out   = (float*)d_out;           // scalar

    int nblocks = NBLOCKS;
    const int cap = (int)(ws_size / sizeof(float));
    if (cap > 0 && cap < nblocks) nblocks = cap;  // defensive: fit partials in ws

    focal_partial_kernel<<<nblocks, 256, 0, stream>>>(x, tgt, alpha, ws, N);
    focal_final_kernel<<<1, 256, 0, stream>>>(ws, nblocks, out, 1.0f / (float)N);
}